// Round 1
// baseline (1893.051 us; speedup 1.0000x reference)
//
#include <hip/hip_runtime.h>
#include <hip/hip_bf16.h>
#include <math.h>

#define EMBD 768
#define FFN_HID 2048
#define HEAD_DIM 64
#define KV_H 5
#define KV_DIM 320
#define Q_H 15
#define QDIM (Q_H * HEAD_DIM) /* 960 */
#define BB 4
#define LL 512
#define LC 2048
#define EPSV 1.1920929e-07f

// ---------------- RMSNorm: one block per row of 768 ----------------
__global__ __launch_bounds__(256) void rmsnorm_kernel(const float* __restrict__ x,
                                                      const float* __restrict__ w,
                                                      float* __restrict__ out) {
  int row = blockIdx.x;  // B*L rows
  const float* xr = x + (size_t)row * EMBD;
  float* orow = out + (size_t)row * EMBD;
  int tid = threadIdx.x;
  float ss = 0.f;
  for (int i = tid; i < EMBD; i += 256) { float v = xr[i]; ss += v * v; }
  for (int off = 32; off > 0; off >>= 1) ss += __shfl_down(ss, off, 64);
  __shared__ float sred[4];
  if ((tid & 63) == 0) sred[tid >> 6] = ss;
  __syncthreads();
  float tot = sred[0] + sred[1] + sred[2] + sred[3];
  float scale = rsqrtf(tot * (1.0f / EMBD) + EPSV);
  for (int i = tid; i < EMBD; i += 256) orow[i] = xr[i] * scale * w[i];
}

// ---------------- fp32 tiled GEMM: C[M,N] = A[M,K] @ W[K,N] (+R) ----------------
// 64x64 tile, BK=16, 256 threads, 4x4 microtile. All dims divide evenly.
template <bool ADD_RES>
__global__ __launch_bounds__(256) void gemm_kernel(const float* __restrict__ A,
                                                   const float* __restrict__ W,
                                                   const float* __restrict__ R,
                                                   float* __restrict__ C,
                                                   int M, int N, int K) {
  __shared__ float As[16][64];
  __shared__ float Ws[16][64];
  int tid = threadIdx.x;
  int tx = tid & 15, ty = tid >> 4;
  int n0 = blockIdx.x * 64, m0 = blockIdx.y * 64;
  float acc[4][4] = {};
  for (int k0 = 0; k0 < K; k0 += 16) {
    {  // A tile 64 rows x 16 cols, transposed into As[k][m]
      int r = tid >> 2;
      int c4 = (tid & 3) * 4;
      const float4 a = *(const float4*)(A + (size_t)(m0 + r) * K + k0 + c4);
      As[c4 + 0][r] = a.x; As[c4 + 1][r] = a.y; As[c4 + 2][r] = a.z; As[c4 + 3][r] = a.w;
    }
    {  // W tile 16 rows x 64 cols
      int c = tid >> 4;
      int j4 = (tid & 15) * 4;
      const float4 w4 = *(const float4*)(W + (size_t)(k0 + c) * N + n0 + j4);
      Ws[c][j4 + 0] = w4.x; Ws[c][j4 + 1] = w4.y; Ws[c][j4 + 2] = w4.z; Ws[c][j4 + 3] = w4.w;
    }
    __syncthreads();
#pragma unroll
    for (int kk = 0; kk < 16; ++kk) {
      float a0 = As[kk][ty * 4 + 0], a1 = As[kk][ty * 4 + 1];
      float a2 = As[kk][ty * 4 + 2], a3 = As[kk][ty * 4 + 3];
      float b0 = Ws[kk][tx * 4 + 0], b1 = Ws[kk][tx * 4 + 1];
      float b2 = Ws[kk][tx * 4 + 2], b3 = Ws[kk][tx * 4 + 3];
      acc[0][0] += a0 * b0; acc[0][1] += a0 * b1; acc[0][2] += a0 * b2; acc[0][3] += a0 * b3;
      acc[1][0] += a1 * b0; acc[1][1] += a1 * b1; acc[1][2] += a1 * b2; acc[1][3] += a1 * b3;
      acc[2][0] += a2 * b0; acc[2][1] += a2 * b1; acc[2][2] += a2 * b2; acc[2][3] += a2 * b3;
      acc[3][0] += a3 * b0; acc[3][1] += a3 * b1; acc[3][2] += a3 * b2; acc[3][3] += a3 * b3;
    }
    __syncthreads();
  }
#pragma unroll
  for (int i = 0; i < 4; ++i)
#pragma unroll
    for (int j = 0; j < 4; ++j) {
      size_t idx = (size_t)(m0 + ty * 4 + i) * N + n0 + tx * 4 + j;
      C[idx] = acc[i][j] + (ADD_RES ? R[idx] : 0.f);
    }
}

// ---------------- RoPE on q: layout [B*L, Q_H, 64] ----------------
__global__ __launch_bounds__(256) void rope_kernel(float* __restrict__ q) {
  int idx = blockIdx.x * 256 + threadIdx.x;  // B*L*Q_H*32 total
  int d = idx & 31;
  int h = (idx >> 5) % Q_H;
  int bl = idx / (32 * Q_H);
  int l = bl & (LL - 1);
  float* qp = q + (size_t)bl * QDIM + h * HEAD_DIM;
  float ts = powf(10000.f, d * (1.f / 32.f));
  float rad = (float)l / ts;
  float s, c;
  sincosf(rad, &s, &c);
  float q1 = qp[d], q2 = qp[d + 32];
  qp[d] = q1 * c - q2 * s;
  qp[d + 32] = q2 * c + q1 * s;
}

// ---------------- attention: block = (b, h, 4 l's); full softmax in LDS ----------------
#define TLQ 4
__global__ __launch_bounds__(256) void attn_kernel(const float* __restrict__ q,
                                                   const float* __restrict__ k,
                                                   const float* __restrict__ v,
                                                   float* __restrict__ ctx) {
  int lt = blockIdx.x, h = blockIdx.y, b = blockIdx.z;
  int kvh = h / 3;  // == h*5//15
  int l0 = lt * TLQ;
  __shared__ float sQ[TLQ][HEAD_DIM];
  __shared__ float sS[TLQ][LC];
  __shared__ float red[4];
  __shared__ float part[4][TLQ][HEAD_DIM];
  int tid = threadIdx.x;
  for (int i = tid; i < TLQ * HEAD_DIM; i += 256) {
    int li = i >> 6, d = i & 63;
    sQ[li][d] = q[(size_t)(b * LL + l0 + li) * QDIM + h * HEAD_DIM + d];
  }
  __syncthreads();
  // scores
  float lmax[TLQ] = {-1e30f, -1e30f, -1e30f, -1e30f};
  for (int m = tid; m < LC; m += 256) {
    const float* kr = k + (size_t)(b * LC + m) * KV_DIM + kvh * HEAD_DIM;
    float a[TLQ] = {0.f, 0.f, 0.f, 0.f};
#pragma unroll
    for (int c = 0; c < HEAD_DIM; c += 4) {
      float4 kf = *(const float4*)(kr + c);
#pragma unroll
      for (int li = 0; li < TLQ; ++li)
        a[li] += kf.x * sQ[li][c] + kf.y * sQ[li][c + 1] + kf.z * sQ[li][c + 2] +
                 kf.w * sQ[li][c + 3];
    }
#pragma unroll
    for (int li = 0; li < TLQ; ++li) {
      float s = a[li] * 0.125f;
      sS[li][m] = s;
      lmax[li] = fmaxf(lmax[li], s);
    }
  }
  __syncthreads();
  float linv[TLQ];
  for (int li = 0; li < TLQ; ++li) {
    float vmax = lmax[li];
    for (int off = 32; off > 0; off >>= 1) vmax = fmaxf(vmax, __shfl_down(vmax, off, 64));
    if ((tid & 63) == 0) red[tid >> 6] = vmax;
    __syncthreads();
    vmax = fmaxf(fmaxf(red[0], red[1]), fmaxf(red[2], red[3]));
    __syncthreads();
    float lsum = 0.f;
    for (int m = tid; m < LC; m += 256) {
      float p = __expf(sS[li][m] - vmax);
      sS[li][m] = p;
      lsum += p;
    }
    for (int off = 32; off > 0; off >>= 1) lsum += __shfl_down(lsum, off, 64);
    if ((tid & 63) == 0) red[tid >> 6] = lsum;
    __syncthreads();
    linv[li] = 1.f / (red[0] + red[1] + red[2] + red[3]);
    __syncthreads();
  }
  // ctx = P @ V
  int d = tid & 63, ch = tid >> 6;
  float acc[TLQ] = {0.f, 0.f, 0.f, 0.f};
  const float* vb = v + (size_t)(b * LC) * KV_DIM + kvh * HEAD_DIM + d;
  for (int m = ch * 512; m < ch * 512 + 512; ++m) {
    float vv = vb[(size_t)m * KV_DIM];
#pragma unroll
    for (int li = 0; li < TLQ; ++li) acc[li] += sS[li][m] * vv;
  }
#pragma unroll
  for (int li = 0; li < TLQ; ++li) part[ch][li][d] = acc[li];
  __syncthreads();
  {
    int li = tid >> 6, dd = tid & 63;
    float s = part[0][li][dd] + part[1][li][dd] + part[2][li][dd] + part[3][li][dd];
    ctx[(size_t)(b * LL + l0 + li) * QDIM + h * HEAD_DIM + dd] = s * linv[li];
  }
}

// ---------------- h = silu(g) * u (in-place into g allowed) ----------------
__global__ __launch_bounds__(256) void silu_mul_kernel(const float* __restrict__ g,
                                                       const float* __restrict__ u,
                                                       float* __restrict__ h, int n) {
  int i = blockIdx.x * 256 + threadIdx.x;
  if (i < n) {
    float gv = g[i];
    h[i] = gv / (1.f + __expf(-gv)) * u[i];
  }
}

extern "C" void kernel_launch(void* const* d_in, const int* in_sizes, int n_in,
                              void* d_out, int out_size, void* d_ws, size_t ws_size,
                              hipStream_t stream) {
  const float* x      = (const float*)d_in[0];
  const float* text_k = (const float*)d_in[1];
  const float* text_v = (const float*)d_in[2];
  const float* ln1_w  = (const float*)d_in[3];
  const float* ln2_w  = (const float*)d_in[4];
  const float* wq     = (const float*)d_in[5];
  const float* wk     = (const float*)d_in[6];
  const float* wv     = (const float*)d_in[7];
  const float* wo     = (const float*)d_in[8];
  const float* w_gate = (const float*)d_in[9];
  const float* w_up   = (const float*)d_in[10];
  const float* w_down = (const float*)d_in[11];
  float* out = (float*)d_out;
  float* ws = (float*)d_ws;

  const int BL = BB * LL;       // 2048
  const int BLC = BB * LC;      // 8192
  // workspace layout (floats), with aliased reuse; peak 12.32M floats = 49.3 MB
  float* xnorm = ws;                         // [0, 1.57M)   reused as xn2
  float* qbuf  = ws + 1572864;               // [1.57M, 3.54M)
  float* kbuf  = qbuf + 1966080;             // [3.54M, 6.16M)
  float* vbuf  = kbuf + 2621440;             // [6.16M, 8.78M)
  float* ctx   = vbuf + 2621440;             // [8.78M, 10.75M)
  float* x2    = ctx + 1966080;              // [10.75M, 12.32M)
  float* g     = qbuf;                       // reuse (q/k dead after attn+wo)
  float* u     = qbuf + 4194304;             // reuse (v/ctx dead after wo)

  // 1. rmsnorm(x) -> xnorm
  rmsnorm_kernel<<<BL, 256, 0, stream>>>(x, ln1_w, xnorm);
  // 2. q = xnorm @ wq  [2048,768]@[768,960]
  gemm_kernel<false><<<dim3(QDIM / 64, BL / 64), 256, 0, stream>>>(xnorm, wq, nullptr, qbuf, BL, QDIM, EMBD);
  // 3. rope(q)
  rope_kernel<<<(BL * Q_H * 32) / 256, 256, 0, stream>>>(qbuf);
  // 4. k = text_k @ wk  [8192,320]@[320,320]
  gemm_kernel<false><<<dim3(KV_DIM / 64, BLC / 64), 256, 0, stream>>>(text_k, wk, nullptr, kbuf, BLC, KV_DIM, KV_DIM);
  // 5. v = text_v @ wv
  gemm_kernel<false><<<dim3(KV_DIM / 64, BLC / 64), 256, 0, stream>>>(text_v, wv, nullptr, vbuf, BLC, KV_DIM, KV_DIM);
  // 6. attention -> ctx
  attn_kernel<<<dim3(LL / TLQ, Q_H, BB), 256, 0, stream>>>(qbuf, kbuf, vbuf, ctx);
  // 7. x2 = ctx @ wo + x
  gemm_kernel<true><<<dim3(EMBD / 64, BL / 64), 256, 0, stream>>>(ctx, wo, x, x2, BL, EMBD, QDIM);
  // 8. rmsnorm(x2) -> xnorm (reuse)
  rmsnorm_kernel<<<BL, 256, 0, stream>>>(x2, ln2_w, xnorm);
  // 9/10. gate & up
  gemm_kernel<false><<<dim3(FFN_HID / 64, BL / 64), 256, 0, stream>>>(xnorm, w_gate, nullptr, g, BL, FFN_HID, EMBD);
  gemm_kernel<false><<<dim3(FFN_HID / 64, BL / 64), 256, 0, stream>>>(xnorm, w_up, nullptr, u, BL, FFN_HID, EMBD);
  // 11. h = silu(g)*u (in place into g)
  silu_mul_kernel<<<(BL * FFN_HID) / 256, 256, 0, stream>>>(g, u, g, BL * FFN_HID);
  // 12. out = h @ w_down + x2
  gemm_kernel<true><<<dim3(EMBD / 64, BL / 64), 256, 0, stream>>>(g, w_down, x2, out, BL, EMBD, FFN_HID);
}

// Round 2
// 1023.368 us; speedup vs baseline: 1.8498x; 1.8498x over previous
//
#include <hip/hip_runtime.h>
#include <hip/hip_bf16.h>
#include <math.h>

#define EMBD 768
#define FFN_HID 2048
#define HEAD_DIM 64
#define KV_H 5
#define KV_DIM 320
#define Q_H 15
#define QDIM (Q_H * HEAD_DIM) /* 960 */
#define BB 4
#define LL 512
#define LC 2048
#define EPSV 1.1920929e-07f

// ---------------- RMSNorm: one block per row of 768 ----------------
__global__ __launch_bounds__(256) void rmsnorm_kernel(const float* __restrict__ x,
                                                      const float* __restrict__ w,
                                                      float* __restrict__ out) {
  int row = blockIdx.x;  // B*L rows
  const float* xr = x + (size_t)row * EMBD;
  float* orow = out + (size_t)row * EMBD;
  int tid = threadIdx.x;
  float ss = 0.f;
  for (int i = tid; i < EMBD; i += 256) { float v = xr[i]; ss += v * v; }
  for (int off = 32; off > 0; off >>= 1) ss += __shfl_down(ss, off, 64);
  __shared__ float sred[4];
  if ((tid & 63) == 0) sred[tid >> 6] = ss;
  __syncthreads();
  float tot = sred[0] + sred[1] + sred[2] + sred[3];
  float scale = rsqrtf(tot * (1.0f / EMBD) + EPSV);
  for (int i = tid; i < EMBD; i += 256) orow[i] = xr[i] * scale * w[i];
}

// ---------------- fp32 tiled GEMM: C[M,N] = A[M,K] @ W[K,N] (+R) ----------------
template <bool ADD_RES>
__global__ __launch_bounds__(256) void gemm_kernel(const float* __restrict__ A,
                                                   const float* __restrict__ W,
                                                   const float* __restrict__ R,
                                                   float* __restrict__ C,
                                                   int M, int N, int K) {
  __shared__ float As[16][64];
  __shared__ float Ws[16][64];
  int tid = threadIdx.x;
  int tx = tid & 15, ty = tid >> 4;
  int n0 = blockIdx.x * 64, m0 = blockIdx.y * 64;
  float acc[4][4] = {};
  for (int k0 = 0; k0 < K; k0 += 16) {
    {
      int r = tid >> 2;
      int c4 = (tid & 3) * 4;
      const float4 a = *(const float4*)(A + (size_t)(m0 + r) * K + k0 + c4);
      As[c4 + 0][r] = a.x; As[c4 + 1][r] = a.y; As[c4 + 2][r] = a.z; As[c4 + 3][r] = a.w;
    }
    {
      int c = tid >> 4;
      int j4 = (tid & 15) * 4;
      const float4 w4 = *(const float4*)(W + (size_t)(k0 + c) * N + n0 + j4);
      Ws[c][j4 + 0] = w4.x; Ws[c][j4 + 1] = w4.y; Ws[c][j4 + 2] = w4.z; Ws[c][j4 + 3] = w4.w;
    }
    __syncthreads();
#pragma unroll
    for (int kk = 0; kk < 16; ++kk) {
      float a0 = As[kk][ty * 4 + 0], a1 = As[kk][ty * 4 + 1];
      float a2 = As[kk][ty * 4 + 2], a3 = As[kk][ty * 4 + 3];
      float b0 = Ws[kk][tx * 4 + 0], b1 = Ws[kk][tx * 4 + 1];
      float b2 = Ws[kk][tx * 4 + 2], b3 = Ws[kk][tx * 4 + 3];
      acc[0][0] += a0 * b0; acc[0][1] += a0 * b1; acc[0][2] += a0 * b2; acc[0][3] += a0 * b3;
      acc[1][0] += a1 * b0; acc[1][1] += a1 * b1; acc[1][2] += a1 * b2; acc[1][3] += a1 * b3;
      acc[2][0] += a2 * b0; acc[2][1] += a2 * b1; acc[2][2] += a2 * b2; acc[2][3] += a2 * b3;
      acc[3][0] += a3 * b0; acc[3][1] += a3 * b1; acc[3][2] += a3 * b2; acc[3][3] += a3 * b3;
    }
    __syncthreads();
  }
#pragma unroll
  for (int i = 0; i < 4; ++i)
#pragma unroll
    for (int j = 0; j < 4; ++j) {
      size_t idx = (size_t)(m0 + ty * 4 + i) * N + n0 + tx * 4 + j;
      C[idx] = acc[i][j] + (ADD_RES ? R[idx] : 0.f);
    }
}

// ---------------- RoPE on q: layout [B*L, Q_H, 64] ----------------
__global__ __launch_bounds__(256) void rope_kernel(float* __restrict__ q) {
  int idx = blockIdx.x * 256 + threadIdx.x;  // B*L*Q_H*32 total
  int d = idx & 31;
  int h = (idx >> 5) % Q_H;
  int bl = idx / (32 * Q_H);
  int l = bl & (LL - 1);
  float* qp = q + (size_t)bl * QDIM + h * HEAD_DIM;
  float ts = powf(10000.f, d * (1.f / 32.f));
  float rad = (float)l / ts;
  float s, c;
  sincosf(rad, &s, &c);
  float q1 = qp[d], q2 = qp[d + 32];
  qp[d] = q1 * c - q2 * s;
  qp[d + 32] = q2 * c + q1 * s;
}

// ---------------- flash attention: 64 queries x 64-key tiles, fp32 GEMM microtile ----------------
// grid: (LL/64, Q_H, B); 256 threads as 16x16, 4x4 fragment each.
// LDS: Qs (Q^T) + KPs (K^T, later P) + Vs = ~49 KB -> 3 blocks/CU.
__global__ __launch_bounds__(256) void attn_kernel(const float* __restrict__ q,
                                                   const float* __restrict__ k,
                                                   const float* __restrict__ v,
                                                   float* __restrict__ ctx) {
  int lt = blockIdx.x, h = blockIdx.y, b = blockIdx.z;
  int kvh = h / 3;  // == h*KV_H/Q_H
  int l0 = lt * 64;
  __shared__ float Qs[64][65];   // Qs[d][l]
  __shared__ float KPs[64][65];  // K^T: KPs[d][m]; reused as P: KPs[l][m]
  __shared__ float Vs[64][64];   // Vs[m][d]
  int tid = threadIdx.x;
  int tx = tid & 15, ty = tid >> 4;

  const float* qbase = q + (size_t)(b * LL + l0) * QDIM + h * HEAD_DIM;
  const float* kbase = k + (size_t)(b * LC) * KV_DIM + kvh * HEAD_DIM;
  const float* vbase = v + (size_t)(b * LC) * KV_DIM + kvh * HEAD_DIM;

#pragma unroll
  for (int i = 0; i < 4; ++i) {  // Q tile 64x64 -> Qs transposed
    int idx = tid + i * 256;
    int r = idx >> 4, c4 = (idx & 15) * 4;
    float4 t = *(const float4*)(qbase + (size_t)r * QDIM + c4);
    Qs[c4 + 0][r] = t.x; Qs[c4 + 1][r] = t.y; Qs[c4 + 2][r] = t.z; Qs[c4 + 3][r] = t.w;
  }

  float m_i[4] = {-1e30f, -1e30f, -1e30f, -1e30f};
  float l_i[4] = {0.f, 0.f, 0.f, 0.f};
  float acc[4][4] = {};

  for (int m0 = 0; m0 < LC; m0 += 64) {
#pragma unroll
    for (int i = 0; i < 4; ++i) {  // K tile (transposed) + V tile (straight)
      int idx = tid + i * 256;
      int r = idx >> 4, c4 = (idx & 15) * 4;
      float4 t = *(const float4*)(kbase + (size_t)(m0 + r) * KV_DIM + c4);
      KPs[c4 + 0][r] = t.x; KPs[c4 + 1][r] = t.y; KPs[c4 + 2][r] = t.z; KPs[c4 + 3][r] = t.w;
      float4 tv = *(const float4*)(vbase + (size_t)(m0 + r) * KV_DIM + c4);
      *(float4*)(&Vs[r][c4]) = tv;
    }
    __syncthreads();

    // S = (Q @ K^T) / 8
    float s[4][4] = {};
#pragma unroll
    for (int d = 0; d < 64; ++d) {
      float a0 = Qs[d][ty * 4 + 0], a1 = Qs[d][ty * 4 + 1];
      float a2 = Qs[d][ty * 4 + 2], a3 = Qs[d][ty * 4 + 3];
      float b0 = KPs[d][tx * 4 + 0], b1 = KPs[d][tx * 4 + 1];
      float b2 = KPs[d][tx * 4 + 2], b3 = KPs[d][tx * 4 + 3];
      s[0][0] += a0 * b0; s[0][1] += a0 * b1; s[0][2] += a0 * b2; s[0][3] += a0 * b3;
      s[1][0] += a1 * b0; s[1][1] += a1 * b1; s[1][2] += a1 * b2; s[1][3] += a1 * b3;
      s[2][0] += a2 * b0; s[2][1] += a2 * b1; s[2][2] += a2 * b2; s[2][3] += a2 * b3;
      s[3][0] += a3 * b0; s[3][1] += a3 * b1; s[3][2] += a3 * b2; s[3][3] += a3 * b3;
    }

    __syncthreads();  // done reading KPs as K

    // online softmax per row (rows = ty*4+i, replicated across the 16 tx lanes)
#pragma unroll
    for (int i = 0; i < 4; ++i) {
      float mx = fmaxf(fmaxf(s[i][0], s[i][1]), fmaxf(s[i][2], s[i][3])) * 0.125f;
      mx = fmaxf(mx, __shfl_xor(mx, 1, 16));
      mx = fmaxf(mx, __shfl_xor(mx, 2, 16));
      mx = fmaxf(mx, __shfl_xor(mx, 4, 16));
      mx = fmaxf(mx, __shfl_xor(mx, 8, 16));
      float mnew = fmaxf(m_i[i], mx);
      float alpha = __expf(m_i[i] - mnew);
      float rsum = 0.f;
#pragma unroll
      for (int j = 0; j < 4; ++j) {
        float p = __expf(s[i][j] * 0.125f - mnew);
        s[i][j] = p;
        rsum += p;
      }
      rsum += __shfl_xor(rsum, 1, 16);
      rsum += __shfl_xor(rsum, 2, 16);
      rsum += __shfl_xor(rsum, 4, 16);
      rsum += __shfl_xor(rsum, 8, 16);
      l_i[i] = l_i[i] * alpha + rsum;
      m_i[i] = mnew;
#pragma unroll
      for (int j = 0; j < 4; ++j) acc[i][j] *= alpha;
    }

    // P -> LDS (reuse KPs as P[l][m])
#pragma unroll
    for (int i = 0; i < 4; ++i)
#pragma unroll
      for (int j = 0; j < 4; ++j) KPs[ty * 4 + i][tx * 4 + j] = s[i][j];
    __syncthreads();

    // O += P @ V
#pragma unroll
    for (int mm = 0; mm < 64; ++mm) {
      float p0 = KPs[ty * 4 + 0][mm], p1 = KPs[ty * 4 + 1][mm];
      float p2 = KPs[ty * 4 + 2][mm], p3 = KPs[ty * 4 + 3][mm];
      float v0 = Vs[mm][tx * 4 + 0], v1 = Vs[mm][tx * 4 + 1];
      float v2 = Vs[mm][tx * 4 + 2], v3 = Vs[mm][tx * 4 + 3];
      acc[0][0] += p0 * v0; acc[0][1] += p0 * v1; acc[0][2] += p0 * v2; acc[0][3] += p0 * v3;
      acc[1][0] += p1 * v0; acc[1][1] += p1 * v1; acc[1][2] += p1 * v2; acc[1][3] += p1 * v3;
      acc[2][0] += p2 * v0; acc[2][1] += p2 * v1; acc[2][2] += p2 * v2; acc[2][3] += p2 * v3;
      acc[3][0] += p3 * v0; acc[3][1] += p3 * v1; acc[3][2] += p3 * v2; acc[3][3] += p3 * v3;
    }
    __syncthreads();  // before next tile's loads overwrite KPs/Vs
  }

  float* obase = ctx + (size_t)(b * LL + l0) * QDIM + h * HEAD_DIM;
#pragma unroll
  for (int i = 0; i < 4; ++i) {
    float inv = 1.f / l_i[i];
#pragma unroll
    for (int j = 0; j < 4; ++j)
      obase[(size_t)(ty * 4 + i) * QDIM + tx * 4 + j] = acc[i][j] * inv;
  }
}

// ---------------- h = silu(g) * u ----------------
__global__ __launch_bounds__(256) void silu_mul_kernel(const float* __restrict__ g,
                                                       const float* __restrict__ u,
                                                       float* __restrict__ h, int n) {
  int i = blockIdx.x * 256 + threadIdx.x;
  if (i < n) {
    float gv = g[i];
    h[i] = gv / (1.f + __expf(-gv)) * u[i];
  }
}

extern "C" void kernel_launch(void* const* d_in, const int* in_sizes, int n_in,
                              void* d_out, int out_size, void* d_ws, size_t ws_size,
                              hipStream_t stream) {
  const float* x      = (const float*)d_in[0];
  const float* text_k = (const float*)d_in[1];
  const float* text_v = (const float*)d_in[2];
  const float* ln1_w  = (const float*)d_in[3];
  const float* ln2_w  = (const float*)d_in[4];
  const float* wq     = (const float*)d_in[5];
  const float* wk     = (const float*)d_in[6];
  const float* wv     = (const float*)d_in[7];
  const float* wo     = (const float*)d_in[8];
  const float* w_gate = (const float*)d_in[9];
  const float* w_up   = (const float*)d_in[10];
  const float* w_down = (const float*)d_in[11];
  float* out = (float*)d_out;
  float* ws = (float*)d_ws;

  const int BL = BB * LL;   // 2048
  const int BLC = BB * LC;  // 8192
  float* xnorm = ws;
  float* qbuf  = ws + 1572864;
  float* kbuf  = qbuf + 1966080;
  float* vbuf  = kbuf + 2621440;
  float* ctx   = vbuf + 2621440;
  float* x2    = ctx + 1966080;
  float* g     = qbuf;
  float* u     = qbuf + 4194304;

  rmsnorm_kernel<<<BL, 256, 0, stream>>>(x, ln1_w, xnorm);
  gemm_kernel<false><<<dim3(QDIM / 64, BL / 64), 256, 0, stream>>>(xnorm, wq, nullptr, qbuf, BL, QDIM, EMBD);
  rope_kernel<<<(BL * Q_H * 32) / 256, 256, 0, stream>>>(qbuf);
  gemm_kernel<false><<<dim3(KV_DIM / 64, BLC / 64), 256, 0, stream>>>(text_k, wk, nullptr, kbuf, BLC, KV_DIM, KV_DIM);
  gemm_kernel<false><<<dim3(KV_DIM / 64, BLC / 64), 256, 0, stream>>>(text_v, wv, nullptr, vbuf, BLC, KV_DIM, KV_DIM);
  attn_kernel<<<dim3(LL / 64, Q_H, BB), 256, 0, stream>>>(qbuf, kbuf, vbuf, ctx);
  gemm_kernel<true><<<dim3(EMBD / 64, BL / 64), 256, 0, stream>>>(ctx, wo, x, x2, BL, EMBD, QDIM);
  rmsnorm_kernel<<<BL, 256, 0, stream>>>(x2, ln2_w, xnorm);
  gemm_kernel<false><<<dim3(FFN_HID / 64, BL / 64), 256, 0, stream>>>(xnorm, w_gate, nullptr, g, BL, FFN_HID, EMBD);
  gemm_kernel<false><<<dim3(FFN_HID / 64, BL / 64), 256, 0, stream>>>(xnorm, w_up, nullptr, u, BL, FFN_HID, EMBD);
  silu_mul_kernel<<<(BL * FFN_HID) / 256, 256, 0, stream>>>(g, u, g, BL * FFN_HID);
  gemm_kernel<true><<<dim3(EMBD / 64, BL / 64), 256, 0, stream>>>(g, w_down, x2, out, BL, EMBD, FFN_HID);
}

// Round 3
// 337.433 us; speedup vs baseline: 5.6101x; 3.0328x over previous
//
#include <hip/hip_runtime.h>
#include <hip/hip_bf16.h>
#include <math.h>

#define EMBD 768
#define FFN_HID 2048
#define HEAD_DIM 64
#define KV_H 5
#define KV_DIM 320
#define Q_H 15
#define QDIM (Q_H * HEAD_DIM) /* 960 */
#define BB 4
#define LL 512
#define LC 2048
#define EPSV 1.1920929e-07f

typedef __attribute__((ext_vector_type(8))) __bf16 bf16x8;
typedef __attribute__((ext_vector_type(8))) short short8;
typedef __attribute__((ext_vector_type(4))) float floatx4;
typedef unsigned short ushort;

__device__ inline ushort f2bf(float f) {
  union { float f; unsigned u; } c; c.f = f;
  unsigned r = c.u + 0x7FFF + ((c.u >> 16) & 1);
  return (ushort)(r >> 16);
}
__device__ inline float bf2f(ushort s) {
  union { unsigned u; float f; } c; c.u = ((unsigned)s) << 16;
  return c.f;
}

// ---------------- RMSNorm fp32 in -> bf16 out ----------------
__global__ __launch_bounds__(256) void rmsnorm_kernel(const float* __restrict__ x,
                                                      const float* __restrict__ w,
                                                      ushort* __restrict__ out) {
  int row = blockIdx.x;
  const float* xr = x + (size_t)row * EMBD;
  ushort* orow = out + (size_t)row * EMBD;
  int tid = threadIdx.x;
  float ss = 0.f;
  for (int i = tid; i < EMBD; i += 256) { float v = xr[i]; ss += v * v; }
  for (int off = 32; off > 0; off >>= 1) ss += __shfl_down(ss, off, 64);
  __shared__ float sred[4];
  if ((tid & 63) == 0) sred[tid >> 6] = ss;
  __syncthreads();
  float tot = sred[0] + sred[1] + sred[2] + sred[3];
  float scale = rsqrtf(tot * (1.0f / EMBD) + EPSV);
  for (int i = tid; i < EMBD; i += 256) orow[i] = f2bf(xr[i] * scale * w[i]);
}

// ---------------- fp32 -> bf16 convert ----------------
__global__ __launch_bounds__(256) void conv_f2b(const float* __restrict__ in,
                                                ushort* __restrict__ out, int n4) {
  int i = blockIdx.x * 256 + threadIdx.x;
  if (i < n4) {
    float4 f = *(const float4*)(in + (size_t)i * 4);
    ushort* o = out + (size_t)i * 4;
    o[0] = f2bf(f.x); o[1] = f2bf(f.y); o[2] = f2bf(f.z); o[3] = f2bf(f.w);
  }
}

// ---------------- weight transpose: fp32 W[K][N] -> bf16 Wt[N][K] ----------------
__global__ __launch_bounds__(256) void transpose_w(const float* __restrict__ W,
                                                   ushort* __restrict__ Wt, int K, int N) {
  __shared__ ushort T[64][72];
  int k0 = blockIdx.y * 64, n0 = blockIdx.x * 64;
  int tid = threadIdx.x;
  int r = tid >> 2, cb = (tid & 3) * 16;
#pragma unroll
  for (int i = 0; i < 16; i += 4) {
    float4 f = *(const float4*)(W + (size_t)(k0 + r) * N + n0 + cb + i);
    T[r][cb + i + 0] = f2bf(f.x); T[r][cb + i + 1] = f2bf(f.y);
    T[r][cb + i + 2] = f2bf(f.z); T[r][cb + i + 3] = f2bf(f.w);
  }
  __syncthreads();
#pragma unroll
  for (int i = 0; i < 2; ++i) {
    short8 v;
#pragma unroll
    for (int j = 0; j < 8; ++j) v[j] = (short)T[cb + i * 8 + j][r];
    *(short8*)(Wt + (size_t)(n0 + r) * K + k0 + cb + i * 8) = v;
  }
}

// ---------------- V transpose: bf16 v[B*Lc][320] -> vt[(b*5+kvh)*64 + d][Lc] ----------------
__global__ __launch_bounds__(256) void transpose_v(const ushort* __restrict__ v,
                                                   ushort* __restrict__ vt) {
  __shared__ ushort T[64][72];
  int m0 = blockIdx.x * 64, kvh = blockIdx.y, b = blockIdx.z;
  int tid = threadIdx.x;
  int r = tid >> 2, cb = (tid & 3) * 16;
  const ushort* src = v + (size_t)(b * LC + m0 + r) * KV_DIM + kvh * HEAD_DIM + cb;
  *(short8*)&T[r][cb] = *(const short8*)src;
  *(short8*)&T[r][cb + 8] = *(const short8*)(src + 8);
  __syncthreads();
#pragma unroll
  for (int i = 0; i < 2; ++i) {
    short8 o;
#pragma unroll
    for (int j = 0; j < 8; ++j) o[j] = (short)T[cb + i * 8 + j][r];
    *(short8*)(vt + ((size_t)(b * KV_H + kvh) * 64 + r) * LC + m0 + cb + i * 8) = o;
  }
}

// ---------------- RoPE on bf16 q ----------------
__global__ __launch_bounds__(256) void rope_kernel(const ushort* __restrict__ qi,
                                                   ushort* __restrict__ qo) {
  int idx = blockIdx.x * 256 + threadIdx.x;  // B*L*Q_H*32
  int d = idx & 31;
  int h = (idx >> 5) % Q_H;
  int bl = idx / (32 * Q_H);
  int l = bl & (LL - 1);
  size_t base = (size_t)bl * QDIM + h * HEAD_DIM;
  float ts = powf(10000.f, d * (1.f / 32.f));
  float rad = (float)l / ts;
  float s, c;
  sincosf(rad, &s, &c);
  float q1 = bf2f(qi[base + d]), q2 = bf2f(qi[base + d + 32]);
  qo[base + d] = f2bf(q1 * c - q2 * s);
  qo[base + d + 32] = f2bf(q2 * c + q1 * s);
}

// ---------------- bf16 MFMA GEMM: C[M,N] = A[M,K] @ Bt[N,K]^T ----------------
// OM: 0 = f32 out, 1 = f32 + residual Rf, 2 = bf16 out, 3 = bf16 silu(Rg)*acc
template <int OM>
__global__ __launch_bounds__(256) void gemm_bt(const ushort* __restrict__ A,
                                               const ushort* __restrict__ Bt,
                                               const float* __restrict__ Rf,
                                               const ushort* __restrict__ Rg,
                                               void* __restrict__ Cout,
                                               int M, int N, int K) {
  __shared__ ushort As[128][72];
  __shared__ ushort Bs[64][72];
  int tid = threadIdx.x;
  int w = tid >> 6, lane = tid & 63;
  int lm = lane & 15, lq = lane >> 4;
  int m0 = blockIdx.y * 128, n0 = blockIdx.x * 64;
  int wm = (w & 1) * 64, wn = (w >> 1) * 32;
  floatx4 acc[4][2];
#pragma unroll
  for (int i = 0; i < 4; ++i)
#pragma unroll
    for (int j = 0; j < 2; ++j) acc[i][j] = (floatx4){0.f, 0.f, 0.f, 0.f};
  int ar = tid >> 1, ac = (tid & 1) * 32;
  int br = tid >> 2, bc = (tid & 3) * 16;
  for (int k0 = 0; k0 < K; k0 += 64) {
    const ushort* ag = A + (size_t)(m0 + ar) * K + k0 + ac;
    *(short8*)&As[ar][ac] = *(const short8*)ag;
    *(short8*)&As[ar][ac + 8] = *(const short8*)(ag + 8);
    *(short8*)&As[ar][ac + 16] = *(const short8*)(ag + 16);
    *(short8*)&As[ar][ac + 24] = *(const short8*)(ag + 24);
    const ushort* bg = Bt + (size_t)(n0 + br) * K + k0 + bc;
    *(short8*)&Bs[br][bc] = *(const short8*)bg;
    *(short8*)&Bs[br][bc + 8] = *(const short8*)(bg + 8);
    __syncthreads();
#pragma unroll
    for (int kc = 0; kc < 2; ++kc) {
      bf16x8 af[4], bf[2];
#pragma unroll
      for (int mt = 0; mt < 4; ++mt)
        af[mt] = *(const bf16x8*)&As[wm + mt * 16 + lm][kc * 32 + lq * 8];
#pragma unroll
      for (int nt = 0; nt < 2; ++nt)
        bf[nt] = *(const bf16x8*)&Bs[wn + nt * 16 + lm][kc * 32 + lq * 8];
#pragma unroll
      for (int mt = 0; mt < 4; ++mt)
#pragma unroll
        for (int nt = 0; nt < 2; ++nt)
          acc[mt][nt] = __builtin_amdgcn_mfma_f32_16x16x32_bf16(af[mt], bf[nt], acc[mt][nt], 0, 0, 0);
    }
    __syncthreads();
  }
#pragma unroll
  for (int mt = 0; mt < 4; ++mt)
#pragma unroll
    for (int nt = 0; nt < 2; ++nt)
#pragma unroll
      for (int r = 0; r < 4; ++r) {
        int row = m0 + wm + mt * 16 + lq * 4 + r;
        int col = n0 + wn + nt * 16 + lm;
        size_t idx = (size_t)row * N + col;
        float vv = acc[mt][nt][r];
        if (OM == 0) ((float*)Cout)[idx] = vv;
        if (OM == 1) ((float*)Cout)[idx] = vv + Rf[idx];
        if (OM == 2) ((ushort*)Cout)[idx] = f2bf(vv);
        if (OM == 3) {
          float gv = bf2f(Rg[idx]);
          float hv = gv / (1.f + __expf(-gv)) * vv;
          ((ushort*)Cout)[idx] = f2bf(hv);
        }
      }
}

// ---------------- MFMA flash attention ----------------
// grid (LL/64, Q_H, B); 4 waves, each owns 16 queries; 64-key tiles.
__global__ __launch_bounds__(256) void attn_kernel(const ushort* __restrict__ qb,
                                                   const ushort* __restrict__ kb,
                                                   const ushort* __restrict__ vt,
                                                   ushort* __restrict__ ctx) {
  int lt = blockIdx.x, h = blockIdx.y, b = blockIdx.z;
  int kvh = h / 3;
  int l0 = lt * 64;
  __shared__ ushort Qs[64][72];
  __shared__ ushort Ks[64][72];
  __shared__ ushort Vs[64][72];  // V^T tile: [d][key]
  __shared__ ushort Ps[4][16][72];
  int tid = threadIdx.x;
  int w = tid >> 6, lane = tid & 63, lm = lane & 15, lq = lane >> 4;
  int sr = tid >> 2, sc = (tid & 3) * 16;
  {
    const ushort* qg = qb + (size_t)(b * LL + l0 + sr) * QDIM + h * HEAD_DIM + sc;
    *(short8*)&Qs[sr][sc] = *(const short8*)qg;
    *(short8*)&Qs[sr][sc + 8] = *(const short8*)(qg + 8);
  }
  floatx4 oacc[4];
#pragma unroll
  for (int i = 0; i < 4; ++i) oacc[i] = (floatx4){0.f, 0.f, 0.f, 0.f};
  float m_i[4] = {-1e30f, -1e30f, -1e30f, -1e30f};
  float l_i[4] = {0.f, 0.f, 0.f, 0.f};

  for (int m0 = 0; m0 < LC; m0 += 64) {
    const ushort* kg = kb + (size_t)(b * LC + m0 + sr) * KV_DIM + kvh * HEAD_DIM + sc;
    *(short8*)&Ks[sr][sc] = *(const short8*)kg;
    *(short8*)&Ks[sr][sc + 8] = *(const short8*)(kg + 8);
    const ushort* vg = vt + ((size_t)(b * KV_H + kvh) * 64 + sr) * LC + m0 + sc;
    *(short8*)&Vs[sr][sc] = *(const short8*)vg;
    *(short8*)&Vs[sr][sc + 8] = *(const short8*)(vg + 8);
    __syncthreads();

    floatx4 sacc[4];
#pragma unroll
    for (int nt = 0; nt < 4; ++nt) sacc[nt] = (floatx4){0.f, 0.f, 0.f, 0.f};
#pragma unroll
    for (int kc = 0; kc < 2; ++kc) {
      bf16x8 aq = *(const bf16x8*)&Qs[w * 16 + lm][kc * 32 + lq * 8];
#pragma unroll
      for (int nt = 0; nt < 4; ++nt) {
        bf16x8 bk = *(const bf16x8*)&Ks[nt * 16 + lm][kc * 32 + lq * 8];
        sacc[nt] = __builtin_amdgcn_mfma_f32_16x16x32_bf16(aq, bk, sacc[nt], 0, 0, 0);
      }
    }
    // online softmax; lane owns rows lq*4+r of this wave's 16 queries
#pragma unroll
    for (int r = 0; r < 4; ++r) {
      float mx = fmaxf(fmaxf(sacc[0][r], sacc[1][r]), fmaxf(sacc[2][r], sacc[3][r])) * 0.125f;
      mx = fmaxf(mx, __shfl_xor(mx, 1));
      mx = fmaxf(mx, __shfl_xor(mx, 2));
      mx = fmaxf(mx, __shfl_xor(mx, 4));
      mx = fmaxf(mx, __shfl_xor(mx, 8));
      float mnew = fmaxf(m_i[r], mx);
      float alpha = __expf(m_i[r] - mnew);
      float rs = 0.f;
#pragma unroll
      for (int nt = 0; nt < 4; ++nt) {
        float p = __expf(sacc[nt][r] * 0.125f - mnew);
        sacc[nt][r] = p;
        rs += p;
      }
      rs += __shfl_xor(rs, 1);
      rs += __shfl_xor(rs, 2);
      rs += __shfl_xor(rs, 4);
      rs += __shfl_xor(rs, 8);
      l_i[r] = l_i[r] * alpha + rs;
      m_i[r] = mnew;
#pragma unroll
      for (int dt = 0; dt < 4; ++dt) oacc[dt][r] *= alpha;
#pragma unroll
      for (int nt = 0; nt < 4; ++nt) Ps[w][lq * 4 + r][nt * 16 + lm] = f2bf(sacc[nt][r]);
    }
    __syncthreads();
    // O += P @ V  (A = P[l][key], B^T = Vs[d][key])
#pragma unroll
    for (int kc = 0; kc < 2; ++kc) {
      bf16x8 ap = *(const bf16x8*)&Ps[w][lm][kc * 32 + lq * 8];
#pragma unroll
      for (int dt = 0; dt < 4; ++dt) {
        bf16x8 bv = *(const bf16x8*)&Vs[dt * 16 + lm][kc * 32 + lq * 8];
        oacc[dt] = __builtin_amdgcn_mfma_f32_16x16x32_bf16(ap, bv, oacc[dt], 0, 0, 0);
      }
    }
    __syncthreads();
  }
#pragma unroll
  for (int r = 0; r < 4; ++r) {
    float inv = 1.f / l_i[r];
    int row = l0 + w * 16 + lq * 4 + r;
#pragma unroll
    for (int dt = 0; dt < 4; ++dt)
      ctx[(size_t)(b * LL + row) * QDIM + h * HEAD_DIM + dt * 16 + lm] = f2bf(oacc[dt][r] * inv);
  }
}

extern "C" void kernel_launch(void* const* d_in, const int* in_sizes, int n_in,
                              void* d_out, int out_size, void* d_ws, size_t ws_size,
                              hipStream_t stream) {
  const float* x      = (const float*)d_in[0];
  const float* text_k = (const float*)d_in[1];
  const float* text_v = (const float*)d_in[2];
  const float* ln1_w  = (const float*)d_in[3];
  const float* ln2_w  = (const float*)d_in[4];
  const float* wq     = (const float*)d_in[5];
  const float* wk     = (const float*)d_in[6];
  const float* wv     = (const float*)d_in[7];
  const float* wo     = (const float*)d_in[8];
  const float* w_gate = (const float*)d_in[9];
  const float* w_up   = (const float*)d_in[10];
  const float* w_down = (const float*)d_in[11];
  float* out = (float*)d_out;
  char* base = (char*)d_ws;

  const int BL = BB * LL;   // 2048
  const int BLC = BB * LC;  // 8192

  // byte offsets (see journal: peak 47.1 MB)
  ushort* xnorm = (ushort*)(base + 0);
  ushort* wqt   = (ushort*)(base + 3145728);
  ushort* wkt   = (ushort*)(base + 4620288);
  ushort* wvt   = (ushort*)(base + 4825088);
  ushort* wot   = (ushort*)(base + 5029888);
  ushort* wgt   = (ushort*)(base + 6504448);
  ushort* wut   = (ushort*)(base + 9650176);
  ushort* wdt   = (ushort*)(base + 12795904);
  ushort* kbuf  = (ushort*)(base + 15941632);
  ushort* vtb   = (ushort*)(base + 21184512);
  float*  x2    = (float*) (base + 26427392);
  ushort* qb    = (ushort*)(base + 32718848);
  char* SB = base + 36651008;
  ushort* tk_bf = (ushort*)SB;               // then vbuf, then ctx, then g/h
  ushort* tv_bf = (ushort*)(SB + 5242880);
  ushort* vbuf  = (ushort*)SB;
  ushort* q_raw = (ushort*)(SB + 5242880);
  ushort* ctxb  = (ushort*)SB;
  ushort* gbuf  = (ushort*)SB;

  // prep: converts + weight transposes
  conv_f2b<<<(BLC * KV_DIM / 4 + 255) / 256, 256, 0, stream>>>(text_k, tk_bf, BLC * KV_DIM / 4);
  conv_f2b<<<(BLC * KV_DIM / 4 + 255) / 256, 256, 0, stream>>>(text_v, tv_bf, BLC * KV_DIM / 4);
  transpose_w<<<dim3(QDIM / 64, EMBD / 64), 256, 0, stream>>>(wq, wqt, EMBD, QDIM);
  transpose_w<<<dim3(KV_DIM / 64, KV_DIM / 64), 256, 0, stream>>>(wk, wkt, KV_DIM, KV_DIM);
  transpose_w<<<dim3(KV_DIM / 64, KV_DIM / 64), 256, 0, stream>>>(wv, wvt, KV_DIM, KV_DIM);
  transpose_w<<<dim3(EMBD / 64, QDIM / 64), 256, 0, stream>>>(wo, wot, QDIM, EMBD);
  transpose_w<<<dim3(FFN_HID / 64, EMBD / 64), 256, 0, stream>>>(w_gate, wgt, EMBD, FFN_HID);
  transpose_w<<<dim3(FFN_HID / 64, EMBD / 64), 256, 0, stream>>>(w_up, wut, EMBD, FFN_HID);
  transpose_w<<<dim3(EMBD / 64, FFN_HID / 64), 256, 0, stream>>>(w_down, wdt, FFN_HID, EMBD);
  rmsnorm_kernel<<<BL, 256, 0, stream>>>(x, ln1_w, xnorm);

  // k/v projections (bf16 out), V transpose
  gemm_bt<2><<<dim3(KV_DIM / 64, BLC / 128), 256, 0, stream>>>(tk_bf, wkt, nullptr, nullptr, kbuf, BLC, KV_DIM, KV_DIM);
  gemm_bt<2><<<dim3(KV_DIM / 64, BLC / 128), 256, 0, stream>>>(tv_bf, wvt, nullptr, nullptr, vbuf, BLC, KV_DIM, KV_DIM);
  transpose_v<<<dim3(LC / 64, KV_H, BB), 256, 0, stream>>>(vbuf, vtb);

  // q projection + rope
  gemm_bt<2><<<dim3(QDIM / 64, BL / 128), 256, 0, stream>>>(xnorm, wqt, nullptr, nullptr, q_raw, BL, QDIM, EMBD);
  rope_kernel<<<(BL * Q_H * 32) / 256, 256, 0, stream>>>(q_raw, qb);

  // attention
  attn_kernel<<<dim3(LL / 64, Q_H, BB), 256, 0, stream>>>(qb, kbuf, vtb, ctxb);

  // wo + residual
  gemm_bt<1><<<dim3(EMBD / 64, BL / 128), 256, 0, stream>>>(ctxb, wot, x, nullptr, x2, BL, EMBD, QDIM);

  // FFN
  rmsnorm_kernel<<<BL, 256, 0, stream>>>(x2, ln2_w, xnorm);
  gemm_bt<2><<<dim3(FFN_HID / 64, BL / 128), 256, 0, stream>>>(xnorm, wgt, nullptr, nullptr, gbuf, BL, FFN_HID, EMBD);
  gemm_bt<3><<<dim3(FFN_HID / 64, BL / 128), 256, 0, stream>>>(xnorm, wut, nullptr, gbuf, gbuf, BL, FFN_HID, EMBD);
  gemm_bt<1><<<dim3(EMBD / 64, BL / 128), 256, 0, stream>>>(gbuf, wdt, x2, nullptr, out, BL, EMBD, FFN_HID);
}